// Round 5
// baseline (533.417 us; speedup 1.0000x reference)
//
#include <hip/hip_runtime.h>
#include <hip/hip_bf16.h>

// ---------------------------------------------------------------------------
// Quantum ViT: B=128, T=127, D_IN=48, DK=S=128, H=8, L=6, P=8128
// Inputs: all float32. Output: float32 [B, DK]. bf16 MFMA internals.
//
// attn v2: 256 thr (4 waves x 32 rows), XOR-swizzled LDS (bank-conflict-free,
// no padding), XCD-aware grid (blockIdx&7 = head -> per-XCD L2 holds hb+wts).
// ---------------------------------------------------------------------------

typedef __bf16 bf16x8 __attribute__((ext_vector_type(8)));
typedef float  f32x4  __attribute__((ext_vector_type(4)));
typedef unsigned int u32;

// swizzled LDS index for a 128x128 bf16 tile: chunk(col/8) ^= row&15.
// b128 reads at col%8==0 stay 16-B aligned; 16 lanes reading 16 rows at the
// same col hit 16 distinct chunks = 64 distinct dwords -> 2-way only (free).
__device__ __forceinline__ int sidx(int row, int col)
{
    return row * 128 + ((((col >> 3) ^ (row & 15)) << 3) | (col & 7));
}

// ---------------------------------------------------------------------------
// 0) Vw f32 -> bf16
// ---------------------------------------------------------------------------
__global__ void __launch_bounds__(256)
vw_bf16_kernel(const float* __restrict__ vw, __bf16* __restrict__ cvw)
{
    int i = (blockIdx.x * 256 + threadIdx.x) * 4;
#pragma unroll
    for (int j = 0; j < 4; j++) cvw[i + j] = (__bf16)vw[i + j];
}

// ---------------------------------------------------------------------------
// 0b) sincos table, layer-major: csn[(mat*254 + t)*64 + j] = (cos,sin) for
//     pair i=2j+(t&1) at layer t (identity if inactive/pad).
// ---------------------------------------------------------------------------
__global__ void __launch_bounds__(64)
sincos_kernel(const float* __restrict__ phi, float2* __restrict__ csn)
{
    const int mat = blockIdx.x / 254;
    const int t   = blockIdx.x % 254;
    const int j   = threadIdx.x;

    float th = 0.f;
    if (t < 253) {
        const int p = t & 1, i = 2 * j + p;
        const int lim = min(t, 252 - t);
        if (i <= lim) {
            const int k = (t + i) >> 1;
            th = phi[mat * 8128 + ((k * (k + 1)) >> 1) + (k - i)];
        }
    }
    float sn, cs;
    __sincosf(th, &sn, &cs);
    csn[(mat * 254 + t) * 64 + j] = make_float2(cs, sn);
}

// ---------------------------------------------------------------------------
// 1) W build: 253 parallel Givens layers (time(k,i)=2k-i), table-fed,
//    pipelined 2 layers deep. Output Wt[mat][c][d] = W[d][c] (bf16).
// ---------------------------------------------------------------------------
__global__ void __launch_bounds__(64)
build_w_kernel(const float2* __restrict__ csn, __bf16* __restrict__ wt)
{
    const int mat = blockIdx.x >> 4;
    const int grp = blockIdx.x & 15;
    const int c0  = grp * 8;
    const int lam = threadIdx.x;

    const float2* base = csn + (mat * 254) * 64 + lam;

    float vlo[8], vhi[8];
#pragma unroll
    for (int j = 0; j < 8; j++) {
        vlo[j] = (2 * lam     == c0 + j) ? 1.f : 0.f;
        vhi[j] = (2 * lam + 1 == c0 + j) ? 1.f : 0.f;
    }

    float2 a  = base[0];
    float2 bq = base[64];

    for (int t = 0; t < 252; t += 2) {
        float2 c2 = base[(t + 2) * 64];
        float2 d2 = base[(t + 3) * 64];
        {
            const float cs = a.x, sn = a.y;
#pragma unroll
            for (int j = 0; j < 8; j++) {
                float lo = vlo[j], hi = vhi[j];
                vlo[j] = cs * lo - sn * hi;
                vhi[j] = sn * lo + cs * hi;
            }
        }
        {
            const float cs = bq.x, sn = bq.y;
#pragma unroll
            for (int j = 0; j < 8; j++) {
                float y  = __shfl_down(vlo[j], 1);
                float x  = vhi[j];
                float xn = cs * x - sn * y;
                float yn = sn * x + cs * y;
                vhi[j] = xn;
                float z = __shfl_up(yn, 1);
                if (lam > 0) vlo[j] = z;
            }
        }
        a = c2; bq = d2;
    }
    {
        const float cs = a.x, sn = a.y;
#pragma unroll
        for (int j = 0; j < 8; j++) {
            float lo = vlo[j], hi = vhi[j];
            vlo[j] = cs * lo - sn * hi;
            vhi[j] = sn * lo + cs * hi;
        }
    }

    u32* wtu = (u32*)wt;
#pragma unroll
    for (int j = 0; j < 8; j++) {
        __bf16 va = (__bf16)vlo[j];
        __bf16 vb = (__bf16)vhi[j];
        u32 pk = (u32)__builtin_bit_cast(unsigned short, va)
               | ((u32)__builtin_bit_cast(unsigned short, vb) << 16);
        wtu[mat * 8192 + (c0 + j) * 64 + lam] = pk;
    }
}

// ---------------------------------------------------------------------------
static __device__ __forceinline__ float block_sum_128(float v, float* sred)
{
#pragma unroll
    for (int m = 32; m; m >>= 1) v += __shfl_xor(v, m);
    __syncthreads();
    if ((threadIdx.x & 63) == 0) sred[threadIdx.x >> 6] = v;
    __syncthreads();
    return sred[0] + sred[1];
}

// ---------------------------------------------------------------------------
// 2) embed: tok = x @ Ew^T + eb (class token s=0), LN0 -> h_f32/h_bf16/inv_n
// ---------------------------------------------------------------------------
__global__ void __launch_bounds__(128)
embed_kernel(const float* __restrict__ x,  const float* __restrict__ ew,
             const float* __restrict__ eb, const float* __restrict__ ct,
             const float* __restrict__ g0, const float* __restrict__ b0,
             float* __restrict__ hf, __bf16* __restrict__ hb, float* __restrict__ invn)
{
    __shared__ float sx[48];
    __shared__ float sred[2];
    const int b = blockIdx.x & 127, s = blockIdx.x >> 7, d = threadIdx.x;

    float val;
    if (s == 0) {
        val = ct[d];
    } else {
        if (d < 48) sx[d] = x[(b * 127 + (s - 1)) * 48 + d];
        __syncthreads();
        float aa = 0.f;
#pragma unroll
        for (int f = 0; f < 48; f++) aa = fmaf(sx[f], ew[d * 48 + f], aa);
        val = aa + eb[d];
    }
    float mean = block_sum_128(val, sred) * (1.f / 128.f);
    float xc   = val - mean;
    float var  = block_sum_128(xc * xc, sred) * (1.f / 128.f);
    float y    = xc * rsqrtf(var + 1e-5f) * g0[d] + b0[d];
    float ss   = block_sum_128(y * y, sred);

    const int o = (b * 128 + s) * 128 + d;
    hf[o] = y;
    hb[o] = (__bf16)y;
    if (d == 0) invn[b * 128 + s] = rsqrtf(ss);
}

// ---------------------------------------------------------------------------
// 3) fused attention head: one WG per (head, batch). 256 thr = 4 waves;
//    wave w owns rows w*32..w*32+31 (two 16-row tiles share B-fragment reads).
//    A: T1 = h @ W -> sT   | B: G = T1 @ h^T, softmax -> Pm in sT (wave-priv)
//    C: V = h @ Vw^T       | D: O = Pm @ V, +h, LN, *mw -> hs
//    scores = G^2 * inv_ns * inv_nt * scale
// ---------------------------------------------------------------------------
__global__ void __launch_bounds__(256, 1)
attn_kernel(int l,
            const float*  __restrict__ hf,  const __bf16* __restrict__ hb,
            const float*  __restrict__ invn, const __bf16* __restrict__ wt,
            const __bf16* __restrict__ vw,  const float* __restrict__ vb,
            const float* __restrict__ lng,  const float* __restrict__ lnb,
            const float* __restrict__ mwp,  __bf16* __restrict__ hs)
{
    __shared__ __align__(16) __bf16 sH[128 * 128];
    __shared__ __align__(16) __bf16 sB[128 * 128];
    __shared__ __align__(16) __bf16 sT[128 * 128];
    __shared__ float sInv[128];
    __shared__ float sVb[128];
    __shared__ float sLg[128];
    __shared__ float sLb[128];

    const int tid  = threadIdx.x;
    const int lane = tid & 63, w = tid >> 6;
    const int l15  = lane & 15, quad = lane >> 4;
    const int hh   = blockIdx.x & 7;    // head = XCD id -> per-XCD L2 locality
    const int b    = blockIdx.x >> 3;
    const int lh   = l * 8 + hh;

    const __bf16* hbp = hb + b * 16384;
    const __bf16* wtp = wt + lh * 16384;
    const __bf16* vwp = vw + lh * 16384;

    // ---- stage sH (h) + sB (Wt); prefetch Vw into regs ----
    bf16x8 vwr[8];
#pragma unroll
    for (int c = 0; c < 8; c++) {
        int ch  = tid + c * 256;          // 2048 chunks of 8 bf16
        int row = ch >> 4, cc = ch & 15;
        bf16x8 hv = *(const bf16x8*)(hbp + ch * 8);
        bf16x8 wv = *(const bf16x8*)(wtp + ch * 8);
        vwr[c]    = *(const bf16x8*)(vwp + ch * 8);
        *(bf16x8*)(&sH[sidx(row, cc * 8)]) = hv;
        *(bf16x8*)(&sB[sidx(row, cc * 8)]) = wv;
    }
    if (tid < 128) {
        sInv[tid] = invn[b * 128 + tid];
        sVb[tid]  = vb[lh * 128 + tid];
        sLg[tid]  = lng[lh * 128 + tid];
        sLb[tid]  = lnb[lh * 128 + tid];
    }
    __syncthreads();  // B1

    const int r0   = w * 32;                 // this wave's 32 output rows
    const int kq   = quad * 8;               // frag k-offset
    const int q4   = quad * 4;               // C/D row offset within tile
    const f32x4 vzero = {0.f, 0.f, 0.f, 0.f};

    f32x4 acc[2][8];

    // 128x128 @ 128x128 with both row-tiles sharing each B read
    auto mm = [&](const __bf16* Ab, const __bf16* Bb) {
#pragma unroll
        for (int rt = 0; rt < 2; rt++)
#pragma unroll
            for (int t = 0; t < 8; t++) acc[rt][t] = vzero;
#pragma unroll
        for (int k0 = 0; k0 < 128; k0 += 32) {
            const int kk = k0 + kq;
            bf16x8 a0 = *(const bf16x8*)(&Ab[sidx(r0 + l15, kk)]);
            bf16x8 a1 = *(const bf16x8*)(&Ab[sidx(r0 + 16 + l15, kk)]);
#pragma unroll
            for (int t = 0; t < 8; t++) {
                bf16x8 bb = *(const bf16x8*)(&Bb[sidx(t * 16 + l15, kk)]);
                acc[0][t] = __builtin_amdgcn_mfma_f32_16x16x32_bf16(a0, bb, acc[0][t], 0, 0, 0);
                acc[1][t] = __builtin_amdgcn_mfma_f32_16x16x32_bf16(a1, bb, acc[1][t], 0, 0, 0);
            }
        }
    };

    // ================= Phase A: T1 = h @ W =================
    mm(sH, sB);
#pragma unroll
    for (int rt = 0; rt < 2; rt++)
#pragma unroll
        for (int t = 0; t < 8; t++)
#pragma unroll
            for (int r = 0; r < 4; r++)
                sT[sidx(r0 + rt * 16 + q4 + r, t * 16 + l15)] = (__bf16)acc[rt][t][r];

    __syncthreads();  // B2: all done reading sB(Wt); T1 visible

    // overwrite sB with Vw (prefetched)
#pragma unroll
    for (int c = 0; c < 8; c++) {
        int ch = tid + c * 256; int row = ch >> 4, cc = ch & 15;
        *(bf16x8*)(&sB[sidx(row, cc * 8)]) = vwr[c];
    }

    // ================= Phase B: G = T1 @ h^T =================
    mm(sT, sH);

    // ---- softmax: scores = G^2 * inv_ns * inv_nt * scale ----
    {
        const float scale = 0.08838834764831843f;  // 1/sqrt(128)
        float invt[8];
#pragma unroll
        for (int t = 0; t < 8; t++) invt[t] = sInv[t * 16 + l15];

#pragma unroll
        for (int rt = 0; rt < 2; rt++) {
            float invs[4];
#pragma unroll
            for (int r = 0; r < 4; r++) invs[r] = sInv[r0 + rt * 16 + q4 + r];

            float mx[4] = {-3e38f, -3e38f, -3e38f, -3e38f};
#pragma unroll
            for (int t = 0; t < 8; t++)
#pragma unroll
                for (int r = 0; r < 4; r++) {
                    float g = acc[rt][t][r];
                    float v = g * g * invs[r] * invt[t] * scale;
                    acc[rt][t][r] = v;
                    mx[r] = fmaxf(mx[r], v);
                }
#pragma unroll
            for (int m = 1; m < 16; m <<= 1)
#pragma unroll
                for (int r = 0; r < 4; r++) mx[r] = fmaxf(mx[r], __shfl_xor(mx[r], m));

            float sm[4] = {0.f, 0.f, 0.f, 0.f};
#pragma unroll
            for (int t = 0; t < 8; t++)
#pragma unroll
                for (int r = 0; r < 4; r++) {
                    float e = __expf(acc[rt][t][r] - mx[r]);
                    acc[rt][t][r] = e;
                    sm[r] += e;
                }
#pragma unroll
            for (int m = 1; m < 16; m <<= 1)
#pragma unroll
                for (int r = 0; r < 4; r++) sm[r] += __shfl_xor(sm[r], m);
#pragma unroll
            for (int r = 0; r < 4; r++) sm[r] = 1.0f / sm[r];
#pragma unroll
            for (int t = 0; t < 8; t++)
#pragma unroll
                for (int r = 0; r < 4; r++)
                    sT[sidx(r0 + rt * 16 + q4 + r, t * 16 + l15)] =
                        (__bf16)(acc[rt][t][r] * sm[r]);
        }
    }

    // residual prefetch (consumed in epilogue)
    float hres[2][8][4];
#pragma unroll
    for (int rt = 0; rt < 2; rt++) {
        const float* hfp = hf + (b * 128 + r0 + rt * 16 + q4) * 128;
#pragma unroll
        for (int t = 0; t < 8; t++)
#pragma unroll
            for (int r = 0; r < 4; r++)
                hres[rt][t][r] = hfp[r * 128 + t * 16 + l15];
    }

    __syncthreads();  // B3: Vw->sB visible

    // ================= Phase C: V = h @ Vw^T =================
    mm(sH, sB);
    __syncthreads();  // B4: all done reading sH (phases B & C)

    {   // V^T into sH: sH[e][token]
        float vbv[8];
#pragma unroll
        for (int t = 0; t < 8; t++) vbv[t] = sVb[t * 16 + l15];
#pragma unroll
        for (int rt = 0; rt < 2; rt++)
#pragma unroll
            for (int t = 0; t < 8; t++)
#pragma unroll
                for (int r = 0; r < 4; r++)
                    sH[sidx(t * 16 + l15, r0 + rt * 16 + q4 + r)] =
                        (__bf16)(acc[rt][t][r] + vbv[t]);
    }
    __syncthreads();  // B5

    // ================= Phase D: O = Pm @ V =================
    mm(sT, sH);

    {   // epilogue: +h, LN over d, *merger_w -> hs
        const float mw = mwp[lh];
        float lgv[8], lbv[8];
#pragma unroll
        for (int t = 0; t < 8; t++) {
            lgv[t] = sLg[t * 16 + l15];
            lbv[t] = sLb[t * 16 + l15];
        }
#pragma unroll
        for (int rt = 0; rt < 2; rt++) {
            float sum_[4] = {0.f, 0.f, 0.f, 0.f};
            float sq_[4]  = {0.f, 0.f, 0.f, 0.f};
#pragma unroll
            for (int t = 0; t < 8; t++)
#pragma unroll
                for (int r = 0; r < 4; r++) {
                    float xx = acc[rt][t][r] + hres[rt][t][r];
                    acc[rt][t][r] = xx;
                    sum_[r] += xx;
                    sq_[r]  += xx * xx;
                }
#pragma unroll
            for (int m = 1; m < 16; m <<= 1)
#pragma unroll
                for (int r = 0; r < 4; r++) {
                    sum_[r] += __shfl_xor(sum_[r], m);
                    sq_[r]  += __shfl_xor(sq_[r], m);
                }
            float mean[4], rstd[4];
#pragma unroll
            for (int r = 0; r < 4; r++) {
                mean[r] = sum_[r] * (1.f / 128.f);
                float var = sq_[r] * (1.f / 128.f) - mean[r] * mean[r];
                rstd[r] = rsqrtf(fmaxf(var, 0.f) + 1e-5f);
            }
            __bf16* hsp = hs + ((hh * 128 + b) * 128 + r0 + rt * 16 + q4) * 128;
#pragma unroll
            for (int t = 0; t < 8; t++)
#pragma unroll
                for (int r = 0; r < 4; r++) {
                    float y = (acc[rt][t][r] - mean[r]) * rstd[r] * lgv[t] + lbv[t];
                    hsp[r * 128 + t * 16 + l15] = (__bf16)(y * mw);
                }
        }
    }
}

// ---------------------------------------------------------------------------
// 4) merge heads + prep next layer. Last layer writes f32 out = h[:,127,:].
// ---------------------------------------------------------------------------
__global__ void __launch_bounds__(128)
merge_kernel(const __bf16* __restrict__ hs, const float* __restrict__ mbp, int l,
             float* __restrict__ hf, __bf16* __restrict__ hb, float* __restrict__ invn,
             float* __restrict__ out, int last)
{
    __shared__ float sred[2];
    const int b = blockIdx.x & 127, s = blockIdx.x >> 7, d = threadIdx.x;

    float acc = mbp[l];
#pragma unroll
    for (int h = 0; h < 8; h++)
        acc += (float)hs[((h * 128 + b) * 128 + s) * 128 + d];

    float ss = block_sum_128(acc * acc, sred);

    const int o = (b * 128 + s) * 128 + d;
    hf[o] = acc;
    hb[o] = (__bf16)acc;
    if (d == 0) invn[b * 128 + s] = rsqrtf(ss);
    if (last && s == 127) out[b * 128 + d] = acc;
}

// ---------------------------------------------------------------------------
extern "C" void kernel_launch(void* const* d_in, const int* in_sizes, int n_in,
                              void* d_out, int out_size, void* d_ws, size_t ws_size,
                              hipStream_t stream)
{
    (void)in_sizes; (void)n_in; (void)out_size; (void)ws_size;

    const float* x   = (const float*)d_in[0];
    const float* ew  = (const float*)d_in[1];
    const float* eb  = (const float*)d_in[2];
    const float* ct  = (const float*)d_in[3];
    const float* g0  = (const float*)d_in[4];
    const float* b0  = (const float*)d_in[5];
    const float* vw  = (const float*)d_in[6];
    const float* vb  = (const float*)d_in[7];
    const float* lng = (const float*)d_in[8];
    const float* lnb = (const float*)d_in[9];
    const float* phi = (const float*)d_in[10];
    const float* mw  = (const float*)d_in[11];
    const float* mb  = (const float*)d_in[12];
    float* out = (float*)d_out;

    char* ws = (char*)d_ws;
    __bf16* wt   = (__bf16*)(ws);                 // 1,572,864
    float*  hf   = (float*)(ws + 1572864);        // 8,388,608
    __bf16* hb   = (__bf16*)(ws + 9961472);       // 4,194,304
    float*  invn = (float*)(ws + 14155776);       // 65,536
    __bf16* hs   = (__bf16*)(ws + 14221312);      // 33,554,432
    __bf16* cvw  = (__bf16*)(ws + 47775744);      // 1,572,864
    float2* csn  = (float2*)(ws + 49348608);      // 6,242,304  (~55.6 MB total)

    vw_bf16_kernel<<<768, 256, 0, stream>>>(vw, cvw);
    sincos_kernel<<<48 * 254, 64, 0, stream>>>(phi, csn);
    build_w_kernel<<<768, 64, 0, stream>>>(csn, wt);
    embed_kernel<<<16384, 128, 0, stream>>>(x, ew, eb, ct, g0, b0, hf, hb, invn);
    for (int l = 0; l < 6; l++) {
        attn_kernel<<<1024, 256, 0, stream>>>(l, hf, hb, invn, wt, cvw, vb,
                                              lng, lnb, mw, hs);
        merge_kernel<<<16384, 128, 0, stream>>>(hs, mb, l, hf, hb, invn, out,
                                                (l == 5) ? 1 : 0);
    }
}

// Round 6
// 471.355 us; speedup vs baseline: 1.1317x; 1.1317x over previous
//
#include <hip/hip_runtime.h>
#include <hip/hip_bf16.h>

// ---------------------------------------------------------------------------
// Quantum ViT: B=128, T=127, D_IN=48, DK=S=128, H=8, L=6, P=8128
// Inputs: all float32. Output: float32 [B, DK]. bf16 MFMA internals.
//
// attn v3: 256 thr (4 waves x 32 rows), XOR-swizzled LDS, TWO LDS buffers
// (sH + sY; T1/Pm reuse the Wt buffer; Vw B-frags straight from global in
// fragment-major layout) -> 66 KB LDS -> 2 blocks/CU. Grid = hh*128 + b
// (XCD = b%8: per-XCD working set ~2 MB < 4 MB L2 — measured 12.5 MB fetch).
// ---------------------------------------------------------------------------

typedef __bf16 bf16x8 __attribute__((ext_vector_type(8)));
typedef float  f32x4  __attribute__((ext_vector_type(4)));
typedef unsigned int u32;

// swizzled LDS index for a 128x128 bf16 tile: chunk(col/8) ^= row&15.
// 16 lanes reading 16 rows at one col -> 16 distinct chunks -> 2-way (free).
__device__ __forceinline__ int sidx(int row, int col)
{
    return row * 128 + ((((col >> 3) ^ (row & 15)) << 3) | (col & 7));
}

// ---------------------------------------------------------------------------
// 0) Vw f32 -> bf16, FRAGMENT-MAJOR: cvwf[((lh*8+t)*4+k0)*64+lane][8] holds
//    Vw[lh][t*16+(lane&15)][k0*32+(lane>>4)*8 .. +8] — so a wave's B-frag
//    load for (t,k0) is 64 lanes x 16 B contiguous (one coalesced 1 KB read).
// ---------------------------------------------------------------------------
__global__ void __launch_bounds__(256)
vw_frag_kernel(const float* __restrict__ vw, __bf16* __restrict__ cvwf)
{
    const int f    = blockIdx.x * 256 + threadIdx.x;   // 98304 frags
    const int lane = f & 63;
    const int k0   = (f >> 6) & 3;
    const int t    = (f >> 8) & 7;
    const int lh   = f >> 11;
    const int row  = t * 16 + (lane & 15);
    const int col  = k0 * 32 + (lane >> 4) * 8;

    const float* src = vw + (lh * 128 + row) * 128 + col;
    __bf16* dst = cvwf + f * 8;
#pragma unroll
    for (int j = 0; j < 8; j++) dst[j] = (__bf16)src[j];
}

// ---------------------------------------------------------------------------
// 0b) sincos table, layer-major: csn[(mat*254 + t)*64 + j] = (cos,sin) for
//     pair i=2j+(t&1) at layer t (identity if inactive/pad).
// ---------------------------------------------------------------------------
__global__ void __launch_bounds__(64)
sincos_kernel(const float* __restrict__ phi, float2* __restrict__ csn)
{
    const int mat = blockIdx.x / 254;
    const int t   = blockIdx.x % 254;
    const int j   = threadIdx.x;

    float th = 0.f;
    if (t < 253) {
        const int p = t & 1, i = 2 * j + p;
        const int lim = min(t, 252 - t);
        if (i <= lim) {
            const int k = (t + i) >> 1;
            th = phi[mat * 8128 + ((k * (k + 1)) >> 1) + (k - i)];
        }
    }
    float sn, cs;
    __sincosf(th, &sn, &cs);
    csn[(mat * 254 + t) * 64 + j] = make_float2(cs, sn);
}

// ---------------------------------------------------------------------------
// 1) W build: 253 parallel Givens layers (time(k,i)=2k-i), table-fed,
//    pipelined 2 layers deep. Output Wt[mat][c][d] = W[d][c] (bf16).
// ---------------------------------------------------------------------------
__global__ void __launch_bounds__(64)
build_w_kernel(const float2* __restrict__ csn, __bf16* __restrict__ wt)
{
    const int mat = blockIdx.x >> 4;
    const int grp = blockIdx.x & 15;
    const int c0  = grp * 8;
    const int lam = threadIdx.x;

    const float2* base = csn + (mat * 254) * 64 + lam;

    float vlo[8], vhi[8];
#pragma unroll
    for (int j = 0; j < 8; j++) {
        vlo[j] = (2 * lam     == c0 + j) ? 1.f : 0.f;
        vhi[j] = (2 * lam + 1 == c0 + j) ? 1.f : 0.f;
    }

    float2 a  = base[0];
    float2 bq = base[64];

    for (int t = 0; t < 252; t += 2) {
        float2 c2 = base[(t + 2) * 64];
        float2 d2 = base[(t + 3) * 64];
        {
            const float cs = a.x, sn = a.y;
#pragma unroll
            for (int j = 0; j < 8; j++) {
                float lo = vlo[j], hi = vhi[j];
                vlo[j] = cs * lo - sn * hi;
                vhi[j] = sn * lo + cs * hi;
            }
        }
        {
            const float cs = bq.x, sn = bq.y;
#pragma unroll
            for (int j = 0; j < 8; j++) {
                float y  = __shfl_down(vlo[j], 1);
                float x  = vhi[j];
                float xn = cs * x - sn * y;
                float yn = sn * x + cs * y;
                vhi[j] = xn;
                float z = __shfl_up(yn, 1);
                if (lam > 0) vlo[j] = z;
            }
        }
        a = c2; bq = d2;
    }
    {
        const float cs = a.x, sn = a.y;
#pragma unroll
        for (int j = 0; j < 8; j++) {
            float lo = vlo[j], hi = vhi[j];
            vlo[j] = cs * lo - sn * hi;
            vhi[j] = sn * lo + cs * hi;
        }
    }

    u32* wtu = (u32*)wt;
#pragma unroll
    for (int j = 0; j < 8; j++) {
        __bf16 va = (__bf16)vlo[j];
        __bf16 vb = (__bf16)vhi[j];
        u32 pk = (u32)__builtin_bit_cast(unsigned short, va)
               | ((u32)__builtin_bit_cast(unsigned short, vb) << 16);
        wtu[mat * 8192 + (c0 + j) * 64 + lam] = pk;
    }
}

// ---------------------------------------------------------------------------
static __device__ __forceinline__ float block_sum_128(float v, float* sred)
{
#pragma unroll
    for (int m = 32; m; m >>= 1) v += __shfl_xor(v, m);
    __syncthreads();
    if ((threadIdx.x & 63) == 0) sred[threadIdx.x >> 6] = v;
    __syncthreads();
    return sred[0] + sred[1];
}

// ---------------------------------------------------------------------------
// 2) embed: tok = x @ Ew^T + eb (class token s=0), LN0 -> h_f32/h_bf16/inv_n
// ---------------------------------------------------------------------------
__global__ void __launch_bounds__(128)
embed_kernel(const float* __restrict__ x,  const float* __restrict__ ew,
             const float* __restrict__ eb, const float* __restrict__ ct,
             const float* __restrict__ g0, const float* __restrict__ b0,
             float* __restrict__ hf, __bf16* __restrict__ hb, float* __restrict__ invn)
{
    __shared__ float sx[48];
    __shared__ float sred[2];
    const int b = blockIdx.x & 127, s = blockIdx.x >> 7, d = threadIdx.x;

    float val;
    if (s == 0) {
        val = ct[d];
    } else {
        if (d < 48) sx[d] = x[(b * 127 + (s - 1)) * 48 + d];
        __syncthreads();
        float aa = 0.f;
#pragma unroll
        for (int f = 0; f < 48; f++) aa = fmaf(sx[f], ew[d * 48 + f], aa);
        val = aa + eb[d];
    }
    float mean = block_sum_128(val, sred) * (1.f / 128.f);
    float xc   = val - mean;
    float var  = block_sum_128(xc * xc, sred) * (1.f / 128.f);
    float y    = xc * rsqrtf(var + 1e-5f) * g0[d] + b0[d];
    float ss   = block_sum_128(y * y, sred);

    const int o = (b * 128 + s) * 128 + d;
    hf[o] = y;
    hb[o] = (__bf16)y;
    if (d == 0) invn[b * 128 + s] = rsqrtf(ss);
}

// ---------------------------------------------------------------------------
// 3) fused attention head: one WG per (head, batch). 256 thr = 4 waves;
//    wave w owns rows w*32..w*32+31 (two 16-row tiles share B-frag reads).
//    LDS: sH (h -> V^T) + sY (Wt -> T1 -> Pm). Vw B-frags from global.
//    A: T1 = h @ W        | B: G = T1 @ h^T, softmax -> Pm
//    C: V = h @ Vw^T      | D: O = Pm @ V, +h, LN, *mw -> hs
//    scores = G^2 * inv_ns * inv_nt * scale
// ---------------------------------------------------------------------------
__global__ void __launch_bounds__(256, 2)
attn_kernel(int l,
            const float*  __restrict__ hf,  const __bf16* __restrict__ hb,
            const float*  __restrict__ invn, const __bf16* __restrict__ wt,
            const __bf16* __restrict__ vwf, const float* __restrict__ vb,
            const float* __restrict__ lng,  const float* __restrict__ lnb,
            const float* __restrict__ mwp,  __bf16* __restrict__ hs)
{
    __shared__ __align__(16) __bf16 sH[128 * 128];
    __shared__ __align__(16) __bf16 sY[128 * 128];
    __shared__ float sInv[128];
    __shared__ float sVb[128];
    __shared__ float sLg[128];
    __shared__ float sLb[128];

    const int tid  = threadIdx.x;
    const int lane = tid & 63, w = tid >> 6;
    const int l15  = lane & 15, quad = lane >> 4;
    const int b    = blockIdx.x & 127;   // XCD = b%8 -> ~2 MB/XCD working set
    const int hh   = blockIdx.x >> 7;
    const int lh   = l * 8 + hh;

    const __bf16* hbp = hb + b * 16384;
    const __bf16* wtp = wt + lh * 16384;

    // ---- stage sH (h) + sY (Wt), swizzled ----
#pragma unroll
    for (int c = 0; c < 8; c++) {
        int ch  = tid + c * 256;          // 2048 chunks of 8 bf16
        int row = ch >> 4, cc = ch & 15;
        bf16x8 hv = *(const bf16x8*)(hbp + ch * 8);
        bf16x8 wv = *(const bf16x8*)(wtp + ch * 8);
        *(bf16x8*)(&sH[sidx(row, cc * 8)]) = hv;
        *(bf16x8*)(&sY[sidx(row, cc * 8)]) = wv;
    }
    if (tid < 128) {
        sInv[tid] = invn[b * 128 + tid];
        sVb[tid]  = vb[lh * 128 + tid];
        sLg[tid]  = lng[lh * 128 + tid];
        sLb[tid]  = lnb[lh * 128 + tid];
    }
    __syncthreads();  // B1

    const int r0 = w * 32;               // this wave's 32 output rows
    const int kq = quad * 8;             // frag k-offset
    const int q4 = quad * 4;             // C/D row offset within 16-tile
    const f32x4 vzero = {0.f, 0.f, 0.f, 0.f};

    f32x4 acc[2][8];

    // 32x128 strip of a 128x128 matmul; both row-tiles share each B read
    auto mmL = [&](const __bf16* Ab, const __bf16* Bb) {
#pragma unroll
        for (int rt = 0; rt < 2; rt++)
#pragma unroll
            for (int t = 0; t < 8; t++) acc[rt][t] = vzero;
#pragma unroll
        for (int k0 = 0; k0 < 128; k0 += 32) {
            const int kk = k0 + kq;
            bf16x8 a0 = *(const bf16x8*)(&Ab[sidx(r0 + l15, kk)]);
            bf16x8 a1 = *(const bf16x8*)(&Ab[sidx(r0 + 16 + l15, kk)]);
#pragma unroll
            for (int t = 0; t < 8; t++) {
                bf16x8 bb = *(const bf16x8*)(&Bb[sidx(t * 16 + l15, kk)]);
                acc[0][t] = __builtin_amdgcn_mfma_f32_16x16x32_bf16(a0, bb, acc[0][t], 0, 0, 0);
                acc[1][t] = __builtin_amdgcn_mfma_f32_16x16x32_bf16(a1, bb, acc[1][t], 0, 0, 0);
            }
        }
    };

    // ================= Phase A: T1 = h @ W =================
    mmL(sH, sY);
    __syncthreads();  // B2: all waves done reading sY(Wt)
#pragma unroll
    for (int rt = 0; rt < 2; rt++)
#pragma unroll
        for (int t = 0; t < 8; t++)
#pragma unroll
            for (int r = 0; r < 4; r++)
                sY[sidx(r0 + rt * 16 + q4 + r, t * 16 + l15)] = (__bf16)acc[rt][t][r];
    // no barrier: phase B reads only this wave's own T1 rows

    // ================= Phase B: G = T1 @ h^T =================
    mmL(sY, sH);

    // ---- softmax: scores = G^2 * inv_ns * inv_nt * scale -> Pm in sY ----
    {
        const float scale = 0.08838834764831843f;  // 1/sqrt(128)
        float invt[8];
#pragma unroll
        for (int t = 0; t < 8; t++) invt[t] = sInv[t * 16 + l15];

#pragma unroll
        for (int rt = 0; rt < 2; rt++) {
            float invs[4];
#pragma unroll
            for (int r = 0; r < 4; r++) invs[r] = sInv[r0 + rt * 16 + q4 + r];

            float mx[4] = {-3e38f, -3e38f, -3e38f, -3e38f};
#pragma unroll
            for (int t = 0; t < 8; t++)
#pragma unroll
                for (int r = 0; r < 4; r++) {
                    float g = acc[rt][t][r];
                    float v = g * g * invs[r] * invt[t] * scale;
                    acc[rt][t][r] = v;
                    mx[r] = fmaxf(mx[r], v);
                }
#pragma unroll
            for (int m = 1; m < 16; m <<= 1)
#pragma unroll
                for (int r = 0; r < 4; r++) mx[r] = fmaxf(mx[r], __shfl_xor(mx[r], m));

            float sm[4] = {0.f, 0.f, 0.f, 0.f};
#pragma unroll
            for (int t = 0; t < 8; t++)
#pragma unroll
                for (int r = 0; r < 4; r++) {
                    float e = __expf(acc[rt][t][r] - mx[r]);
                    acc[rt][t][r] = e;
                    sm[r] += e;
                }
#pragma unroll
            for (int m = 1; m < 16; m <<= 1)
#pragma unroll
                for (int r = 0; r < 4; r++) sm[r] += __shfl_xor(sm[r], m);
#pragma unroll
            for (int r = 0; r < 4; r++) sm[r] = 1.0f / sm[r];
#pragma unroll
            for (int t = 0; t < 8; t++)
#pragma unroll
                for (int r = 0; r < 4; r++)
                    sY[sidx(r0 + rt * 16 + q4 + r, t * 16 + l15)] =
                        (__bf16)(acc[rt][t][r] * sm[r]);
        }
    }

    // residual prefetch (consumed in epilogue)
    float hres[2][8][4];
#pragma unroll
    for (int rt = 0; rt < 2; rt++) {
        const float* hfp = hf + (b * 128 + r0 + rt * 16 + q4) * 128;
#pragma unroll
        for (int t = 0; t < 8; t++)
#pragma unroll
            for (int r = 0; r < 4; r++)
                hres[rt][t][r] = hfp[r * 128 + t * 16 + l15];
    }

    // ================= Phase C: V = h @ Vw^T (B-frags from global) ========
    {
        const __bf16* vbase = vwf + (size_t)lh * 16384;  // frag-major head blk
#pragma unroll
        for (int rt = 0; rt < 2; rt++)
#pragma unroll
            for (int t = 0; t < 8; t++) acc[rt][t] = vzero;
#pragma unroll
        for (int k0c = 0; k0c < 4; k0c++) {
            const int kk = k0c * 32 + kq;
            bf16x8 a0 = *(const bf16x8*)(&sH[sidx(r0 + l15, kk)]);
            bf16x8 a1 = *(const bf16x8*)(&sH[sidx(r0 + 16 + l15, kk)]);
#pragma unroll
            for (int t = 0; t < 8; t++) {
                bf16x8 bb = *(const bf16x8*)(vbase + ((t * 4 + k0c) * 64 + lane) * 8);
                acc[0][t] = __builtin_amdgcn_mfma_f32_16x16x32_bf16(a0, bb, acc[0][t], 0, 0, 0);
                acc[1][t] = __builtin_amdgcn_mfma_f32_16x16x32_bf16(a1, bb, acc[1][t], 0, 0, 0);
            }
        }
    }
    __syncthreads();  // B4: all waves done reading sH (phases B & C)

    {   // V^T into sH: sH[e][token]
        float vbv[8];
#pragma unroll
        for (int t = 0; t < 8; t++) vbv[t] = sVb[t * 16 + l15];
#pragma unroll
        for (int rt = 0; rt < 2; rt++)
#pragma unroll
            for (int t = 0; t < 8; t++)
#pragma unroll
                for (int r = 0; r < 4; r++)
                    sH[sidx(t * 16 + l15, r0 + rt * 16 + q4 + r)] =
                        (__bf16)(acc[rt][t][r] + vbv[t]);
    }
    __syncthreads();  // B5

    // ================= Phase D: O = Pm @ V =================
    mmL(sY, sH);

    {   // epilogue: +h, LN over d, *merger_w -> hs
        const float mw = mwp[lh];
        float lgv[8], lbv[8];
#pragma unroll
        for (int t = 0; t < 8; t++) {
            lgv[t] = sLg[t * 16 + l15];
            lbv[t] = sLb[t * 16 + l15];
        }
#pragma unroll
        for (int rt = 0; rt < 2; rt++) {
            float sum_[4] = {0.f, 0.f, 0.f, 0.f};
            float sq_[4]  = {0.f, 0.f, 0.f, 0.f};
#pragma unroll
            for (int t = 0; t < 8; t++)
#pragma unroll
                for (int r = 0; r < 4; r++) {
                    float xx = acc[rt][t][r] + hres[rt][t][r];
                    acc[rt][t][r] = xx;
                    sum_[r] += xx;
                    sq_[r]  += xx * xx;
                }
#pragma unroll
            for (int m = 1; m < 16; m <<= 1)
#pragma unroll
                for (int r = 0; r < 4; r++) {
                    sum_[r] += __shfl_xor(sum_[r], m);
                    sq_[r]  += __shfl_xor(sq_[r], m);
                }
            float mean[4], rstd[4];
#pragma unroll
            for (int r = 0; r < 4; r++) {
                mean[r] = sum_[r] * (1.f / 128.f);
                float var = sq_[r] * (1.f / 128.f) - mean[r] * mean[r];
                rstd[r] = rsqrtf(fmaxf(var, 0.f) + 1e-5f);
            }
            __bf16* hsp = hs + ((hh * 128 + b) * 128 + r0 + rt * 16 + q4) * 128;
#pragma unroll
            for (int t = 0; t < 8; t++)
#pragma unroll
                for (int r = 0; r < 4; r++) {
                    float y = (acc[rt][t][r] - mean[r]) * rstd[r] * lgv[t] + lbv[t];
                    hsp[r * 128 + t * 16 + l15] = (__bf16)(y * mw);
                }
        }
    }
}

// ---------------------------------------------------------------------------
// 4) merge heads + prep next layer. Last layer writes f32 out = h[:,127,:].
// ---------------------------------------------------------------------------
__global__ void __launch_bounds__(128)
merge_kernel(const __bf16* __restrict__ hs, const float* __restrict__ mbp, int l,
             float* __restrict__ hf, __bf16* __restrict__ hb, float* __restrict__ invn,
             float* __restrict__ out, int last)
{
    __shared__ float sred[2];
    const int b = blockIdx.x & 127, s = blockIdx.x >> 7, d = threadIdx.x;

    float acc = mbp[l];
#pragma unroll
    for (int h = 0; h < 8; h++)
        acc += (float)hs[((h * 128 + b) * 128 + s) * 128 + d];

    float ss = block_sum_128(acc * acc, sred);

    const int o = (b * 128 + s) * 128 + d;
    hf[o] = acc;
    hb[o] = (__bf16)acc;
    if (d == 0) invn[b * 128 + s] = rsqrtf(ss);
    if (last && s == 127) out[b * 128 + d] = acc;
}

// ---------------------------------------------------------------------------
extern "C" void kernel_launch(void* const* d_in, const int* in_sizes, int n_in,
                              void* d_out, int out_size, void* d_ws, size_t ws_size,
                              hipStream_t stream)
{
    (void)in_sizes; (void)n_in; (void)out_size; (void)ws_size;

    const float* x   = (const float*)d_in[0];
    const float* ew  = (const float*)d_in[1];
    const float* eb  = (const float*)d_in[2];
    const float* ct  = (const float*)d_in[3];
    const float* g0  = (const float*)d_in[4];
    const float* b0  = (const float*)d_in[5];
    const float* vw  = (const float*)d_in[6];
    const float* vb  = (const float*)d_in[7];
    const float* lng = (const float*)d_in[8];
    const float* lnb = (const float*)d_in[9];
    const float* phi = (const float*)d_in[10];
    const float* mw  = (const float*)d_in[11];
    const float* mb  = (const float*)d_in[12];
    float* out = (float*)d_out;

    char* ws = (char*)d_ws;
    __bf16* wt   = (__bf16*)(ws);                 // 1,572,864
    float*  hf   = (float*)(ws + 1572864);        // 8,388,608
    __bf16* hb   = (__bf16*)(ws + 9961472);       // 4,194,304
    float*  invn = (float*)(ws + 14155776);       // 65,536
    __bf16* hs   = (__bf16*)(ws + 14221312);      // 33,554,432
    __bf16* cvwf = (__bf16*)(ws + 47775744);      // 1,572,864 (frag-major Vw)
    float2* csn  = (float2*)(ws + 49348608);      // 6,242,304  (~55.6 MB total)

    vw_frag_kernel<<<384, 256, 0, stream>>>(vw, cvwf);
    sincos_kernel<<<48 * 254, 64, 0, stream>>>(phi, csn);
    build_w_kernel<<<768, 64, 0, stream>>>(csn, wt);
    embed_kernel<<<16384, 128, 0, stream>>>(x, ew, eb, ct, g0, b0, hf, hb, invn);
    for (int l = 0; l < 6; l++) {
        attn_kernel<<<1024, 256, 0, stream>>>(l, hf, hb, invn, wt, cvwf, vb,
                                              lng, lnb, mw, hs);
        merge_kernel<<<16384, 128, 0, stream>>>(hs, mb, l, hf, hb, invn, out,
                                                (l == 5) ? 1 : 0);
    }
}

// Round 7
// 439.475 us; speedup vs baseline: 1.2138x; 1.0725x over previous
//
#include <hip/hip_runtime.h>
#include <hip/hip_bf16.h>

// ---------------------------------------------------------------------------
// Quantum ViT: B=128, T=127, D_IN=48, DK=S=128, H=8, L=6, P=8128
// Inputs: all float32. Output: float32 [B, DK]. bf16 MFMA internals.
//
// attn v4: 512 thr (8 waves x 16 rows) x 2 blocks/CU = 16 waves/CU (the knob
// R4/R6 never moved: both ran 8 waves/CU and both plateaued at ~50 us).
// Keeps: XOR-swizzled LDS (conflict-free), two LDS buffers (66 KB),
// frag-major Vw read from global, b-major grid (XCD = b%8, 12.5 MB fetch).
// ---------------------------------------------------------------------------

typedef __bf16 bf16x8 __attribute__((ext_vector_type(8)));
typedef float  f32x4  __attribute__((ext_vector_type(4)));
typedef unsigned int u32;

// swizzled LDS index for a 128x128 bf16 tile: chunk(col/8) ^= row&15.
// 16 lanes reading 16 rows at one col -> 16 distinct chunks -> 2-way (free).
__device__ __forceinline__ int sidx(int row, int col)
{
    return row * 128 + ((((col >> 3) ^ (row & 15)) << 3) | (col & 7));
}

// ---------------------------------------------------------------------------
// 0) Vw f32 -> bf16, FRAGMENT-MAJOR: cvwf[((lh*8+t)*4+k0)*64+lane][8] holds
//    Vw[lh][t*16+(lane&15)][k0*32+(lane>>4)*8 .. +8] — a wave's B-frag load
//    for (t,k0) is 64 lanes x 16 B contiguous (one coalesced 1 KB read).
// ---------------------------------------------------------------------------
__global__ void __launch_bounds__(256)
vw_frag_kernel(const float* __restrict__ vw, __bf16* __restrict__ cvwf)
{
    const int f    = blockIdx.x * 256 + threadIdx.x;   // 98304 frags
    const int lane = f & 63;
    const int k0   = (f >> 6) & 3;
    const int t    = (f >> 8) & 7;
    const int lh   = f >> 11;
    const int row  = t * 16 + (lane & 15);
    const int col  = k0 * 32 + (lane >> 4) * 8;

    const float* src = vw + (lh * 128 + row) * 128 + col;
    __bf16* dst = cvwf + f * 8;
#pragma unroll
    for (int j = 0; j < 8; j++) dst[j] = (__bf16)src[j];
}

// ---------------------------------------------------------------------------
// 0b) sincos table, layer-major: csn[(mat*254 + t)*64 + j] = (cos,sin) for
//     pair i=2j+(t&1) at layer t (identity if inactive/pad).
// ---------------------------------------------------------------------------
__global__ void __launch_bounds__(64)
sincos_kernel(const float* __restrict__ phi, float2* __restrict__ csn)
{
    const int mat = blockIdx.x / 254;
    const int t   = blockIdx.x % 254;
    const int j   = threadIdx.x;

    float th = 0.f;
    if (t < 253) {
        const int p = t & 1, i = 2 * j + p;
        const int lim = min(t, 252 - t);
        if (i <= lim) {
            const int k = (t + i) >> 1;
            th = phi[mat * 8128 + ((k * (k + 1)) >> 1) + (k - i)];
        }
    }
    float sn, cs;
    __sincosf(th, &sn, &cs);
    csn[(mat * 254 + t) * 64 + j] = make_float2(cs, sn);
}

// ---------------------------------------------------------------------------
// 1) W build: 253 parallel Givens layers (time(k,i)=2k-i), table-fed,
//    pipelined 2 layers deep. Output Wt[mat][c][d] = W[d][c] (bf16).
// ---------------------------------------------------------------------------
__global__ void __launch_bounds__(64)
build_w_kernel(const float2* __restrict__ csn, __bf16* __restrict__ wt)
{
    const int mat = blockIdx.x >> 4;
    const int grp = blockIdx.x & 15;
    const int c0  = grp * 8;
    const int lam = threadIdx.x;

    const float2* base = csn + (mat * 254) * 64 + lam;

    float vlo[8], vhi[8];
#pragma unroll
    for (int j = 0; j < 8; j++) {
        vlo[j] = (2 * lam     == c0 + j) ? 1.f : 0.f;
        vhi[j] = (2 * lam + 1 == c0 + j) ? 1.f : 0.f;
    }

    float2 a  = base[0];
    float2 bq = base[64];

    for (int t = 0; t < 252; t += 2) {
        float2 c2 = base[(t + 2) * 64];
        float2 d2 = base[(t + 3) * 64];
        {
            const float cs = a.x, sn = a.y;
#pragma unroll
            for (int j = 0; j < 8; j++) {
                float lo = vlo[j], hi = vhi[j];
                vlo[j] = cs * lo - sn * hi;
                vhi[j] = sn * lo + cs * hi;
            }
        }
        {
            const float cs = bq.x, sn = bq.y;
#pragma unroll
            for (int j = 0; j < 8; j++) {
                float y  = __shfl_down(vlo[j], 1);
                float x  = vhi[j];
                float xn = cs * x - sn * y;
                float yn = sn * x + cs * y;
                vhi[j] = xn;
                float z = __shfl_up(yn, 1);
                if (lam > 0) vlo[j] = z;
            }
        }
        a = c2; bq = d2;
    }
    {
        const float cs = a.x, sn = a.y;
#pragma unroll
        for (int j = 0; j < 8; j++) {
            float lo = vlo[j], hi = vhi[j];
            vlo[j] = cs * lo - sn * hi;
            vhi[j] = sn * lo + cs * hi;
        }
    }

    u32* wtu = (u32*)wt;
#pragma unroll
    for (int j = 0; j < 8; j++) {
        __bf16 va = (__bf16)vlo[j];
        __bf16 vb = (__bf16)vhi[j];
        u32 pk = (u32)__builtin_bit_cast(unsigned short, va)
               | ((u32)__builtin_bit_cast(unsigned short, vb) << 16);
        wtu[mat * 8192 + (c0 + j) * 64 + lam] = pk;
    }
}

// ---------------------------------------------------------------------------
static __device__ __forceinline__ float block_sum_128(float v, float* sred)
{
#pragma unroll
    for (int m = 32; m; m >>= 1) v += __shfl_xor(v, m);
    __syncthreads();
    if ((threadIdx.x & 63) == 0) sred[threadIdx.x >> 6] = v;
    __syncthreads();
    return sred[0] + sred[1];
}

// ---------------------------------------------------------------------------
// 2) embed: tok = x @ Ew^T + eb (class token s=0), LN0 -> h_f32/h_bf16/inv_n
// ---------------------------------------------------------------------------
__global__ void __launch_bounds__(128)
embed_kernel(const float* __restrict__ x,  const float* __restrict__ ew,
             const float* __restrict__ eb, const float* __restrict__ ct,
             const float* __restrict__ g0, const float* __restrict__ b0,
             float* __restrict__ hf, __bf16* __restrict__ hb, float* __restrict__ invn)
{
    __shared__ float sx[48];
    __shared__ float sred[2];
    const int b = blockIdx.x & 127, s = blockIdx.x >> 7, d = threadIdx.x;

    float val;
    if (s == 0) {
        val = ct[d];
    } else {
        if (d < 48) sx[d] = x[(b * 127 + (s - 1)) * 48 + d];
        __syncthreads();
        float aa = 0.f;
#pragma unroll
        for (int f = 0; f < 48; f++) aa = fmaf(sx[f], ew[d * 48 + f], aa);
        val = aa + eb[d];
    }
    float mean = block_sum_128(val, sred) * (1.f / 128.f);
    float xc   = val - mean;
    float var  = block_sum_128(xc * xc, sred) * (1.f / 128.f);
    float y    = xc * rsqrtf(var + 1e-5f) * g0[d] + b0[d];
    float ss   = block_sum_128(y * y, sred);

    const int o = (b * 128 + s) * 128 + d;
    hf[o] = y;
    hb[o] = (__bf16)y;
    if (d == 0) invn[b * 128 + s] = rsqrtf(ss);
}

// ---------------------------------------------------------------------------
// 3) fused attention head: one WG per (head, batch). 512 thr = 8 waves,
//    wave w owns rows w*16..w*16+15 of every 128x128 matmul.
//    LDS: sH (h -> V^T) + sY (Wt -> T1 -> Pm). Vw B-frags from global.
//    A: T1 = h @ W        | B: G = T1 @ h^T, softmax -> Pm
//    C: V = h @ Vw^T      | D: O = Pm @ V, +h, LN, *mw -> hs
//    scores = G^2 * inv_ns * inv_nt * scale  (softmax done in base 2)
// ---------------------------------------------------------------------------
__global__ void __launch_bounds__(512, 4)
attn_kernel(int l,
            const float*  __restrict__ hf,  const __bf16* __restrict__ hb,
            const float*  __restrict__ invn, const __bf16* __restrict__ wt,
            const __bf16* __restrict__ vwf, const float* __restrict__ vb,
            const float* __restrict__ lng,  const float* __restrict__ lnb,
            const float* __restrict__ mwp,  __bf16* __restrict__ hs)
{
    __shared__ __align__(16) __bf16 sH[128 * 128];
    __shared__ __align__(16) __bf16 sY[128 * 128];
    __shared__ float sInv[128];
    __shared__ float sVb[128];
    __shared__ float sLg[128];
    __shared__ float sLb[128];

    const int tid  = threadIdx.x;
    const int lane = tid & 63, w = tid >> 6;
    const int l15  = lane & 15, quad = lane >> 4;
    const int b    = blockIdx.x & 127;   // XCD = b%8 -> ~2 MB/XCD working set
    const int hh   = blockIdx.x >> 7;
    const int lh   = l * 8 + hh;

    const __bf16* hbp = hb + b * 16384;
    const __bf16* wtp = wt + lh * 16384;

    // ---- stage sH (h) + sY (Wt), swizzled ----
#pragma unroll
    for (int c = 0; c < 4; c++) {
        int ch  = tid + c * 512;          // 2048 chunks of 8 bf16
        int row = ch >> 4, cc = ch & 15;
        bf16x8 hv = *(const bf16x8*)(hbp + ch * 8);
        bf16x8 wv = *(const bf16x8*)(wtp + ch * 8);
        *(bf16x8*)(&sH[sidx(row, cc * 8)]) = hv;
        *(bf16x8*)(&sY[sidx(row, cc * 8)]) = wv;
    }
    if (tid < 128) {
        sInv[tid] = invn[b * 128 + tid];
        sVb[tid]  = vb[lh * 128 + tid];
        sLg[tid]  = lng[lh * 128 + tid];
        sLb[tid]  = lnb[lh * 128 + tid];
    }
    __syncthreads();  // B1

    const int r0 = w * 16;               // this wave's 16 output rows
    const int kq = quad * 8;             // frag k-offset
    const int q4 = quad * 4;             // C/D row offset within 16-tile
    const f32x4 vzero = {0.f, 0.f, 0.f, 0.f};

    f32x4 acc[8];

    // 16x128 strip of a 128x128 matmul
    auto mmL = [&](const __bf16* Ab, const __bf16* Bb) {
#pragma unroll
        for (int t = 0; t < 8; t++) acc[t] = vzero;
#pragma unroll
        for (int k0 = 0; k0 < 128; k0 += 32) {
            const int kk = k0 + kq;
            bf16x8 a0 = *(const bf16x8*)(&Ab[sidx(r0 + l15, kk)]);
#pragma unroll
            for (int t = 0; t < 8; t++) {
                bf16x8 bb = *(const bf16x8*)(&Bb[sidx(t * 16 + l15, kk)]);
                acc[t] = __builtin_amdgcn_mfma_f32_16x16x32_bf16(a0, bb, acc[t], 0, 0, 0);
            }
        }
    };

    // ================= Phase A: T1 = h @ W =================
    mmL(sH, sY);
    __syncthreads();  // B2: all waves done reading sY(Wt)
#pragma unroll
    for (int t = 0; t < 8; t++)
#pragma unroll
        for (int r = 0; r < 4; r++)
            sY[sidx(r0 + q4 + r, t * 16 + l15)] = (__bf16)acc[t][r];
    // no barrier: phase B reads only this wave's own T1 rows

    // ================= Phase B: G = T1 @ h^T =================
    mmL(sY, sH);

    // ---- softmax (base 2): v = G^2*inv_s*inv_t*(scale*log2e) -> Pm in sY ---
    {
        const float scale2 = 0.08838834764831843f * 1.4426950408889634f;
        float invt[8];
#pragma unroll
        for (int t = 0; t < 8; t++) invt[t] = sInv[t * 16 + l15];
        float invs[4];
#pragma unroll
        for (int r = 0; r < 4; r++) invs[r] = sInv[r0 + q4 + r];

        float mx[4] = {-3e38f, -3e38f, -3e38f, -3e38f};
#pragma unroll
        for (int t = 0; t < 8; t++)
#pragma unroll
            for (int r = 0; r < 4; r++) {
                float g = acc[t][r];
                float v = g * g * invs[r] * invt[t] * scale2;
                acc[t][r] = v;
                mx[r] = fmaxf(mx[r], v);
            }
#pragma unroll
        for (int m = 1; m < 16; m <<= 1)
#pragma unroll
            for (int r = 0; r < 4; r++) mx[r] = fmaxf(mx[r], __shfl_xor(mx[r], m));

        float sm[4] = {0.f, 0.f, 0.f, 0.f};
#pragma unroll
        for (int t = 0; t < 8; t++)
#pragma unroll
            for (int r = 0; r < 4; r++) {
                float e = exp2f(acc[t][r] - mx[r]);
                acc[t][r] = e;
                sm[r] += e;
            }
#pragma unroll
        for (int m = 1; m < 16; m <<= 1)
#pragma unroll
            for (int r = 0; r < 4; r++) sm[r] += __shfl_xor(sm[r], m);
#pragma unroll
        for (int r = 0; r < 4; r++) sm[r] = 1.0f / sm[r];
#pragma unroll
        for (int t = 0; t < 8; t++)
#pragma unroll
            for (int r = 0; r < 4; r++)
                sY[sidx(r0 + q4 + r, t * 16 + l15)] = (__bf16)(acc[t][r] * sm[r]);
    }

    // residual prefetch (consumed in epilogue)
    float hres[8][4];
    {
        const float* hfp = hf + (b * 128 + r0 + q4) * 128;
#pragma unroll
        for (int t = 0; t < 8; t++)
#pragma unroll
            for (int r = 0; r < 4; r++)
                hres[t][r] = hfp[r * 128 + t * 16 + l15];
    }

    // ================= Phase C: V = h @ Vw^T (B-frags from global) ========
    {
        const __bf16* vbase = vwf + (size_t)lh * 16384;  // frag-major head blk
#pragma unroll
        for (int t = 0; t < 8; t++) acc[t] = vzero;
#pragma unroll
        for (int k0c = 0; k0c < 4; k0c++) {
            const int kk = k0c * 32 + kq;
            bf16x8 a0 = *(const bf16x8*)(&sH[sidx(r0 + l15, kk)]);
#pragma unroll
            for (int t = 0; t < 8; t++) {
                bf16x8 bb = *(const bf16x8*)(vbase + ((t * 4 + k0c) * 64 + lane) * 8);
                acc[t] = __builtin_amdgcn_mfma_f32_16x16x32_bf16(a0, bb, acc[t], 0, 0, 0);
            }
        }
    }
    __syncthreads();  // B4: all waves done reading sH (phases B & C)

    {   // V^T into sH: sH[e][token]
        float vbv[8];
#pragma unroll
        for (int t = 0; t < 8; t++) vbv[t] = sVb[t * 16 + l15];
#pragma unroll
        for (int t = 0; t < 8; t++)
#pragma unroll
            for (int r = 0; r < 4; r++)
                sH[sidx(t * 16 + l15, r0 + q4 + r)] = (__bf16)(acc[t][r] + vbv[t]);
    }
    __syncthreads();  // B5

    // ================= Phase D: O = Pm @ V =================
    mmL(sY, sH);

    {   // epilogue: +h, LN over d, *merger_w -> hs
        const float mw = mwp[lh];
        float lgv[8], lbv[8];
#pragma unroll
        for (int t = 0; t < 8; t++) {
            lgv[t] = sLg[t * 16 + l15];
            lbv[t] = sLb[t * 16 + l15];
        }
        float sum_[4] = {0.f, 0.f, 0.f, 0.f};
        float sq_[4]  = {0.f, 0.f, 0.f, 0.f};
#pragma unroll
        for (int t = 0; t < 8; t++)
#pragma unroll
            for (int r = 0; r < 4; r++) {
                float xx = acc[t][r] + hres[t][r];
                acc[t][r] = xx;
                sum_[r] += xx;
                sq_[r]  += xx * xx;
            }
#pragma unroll
        for (int m = 1; m < 16; m <<= 1)
#pragma unroll
            for (int r = 0; r < 4; r++) {
                sum_[r] += __shfl_xor(sum_[r], m);
                sq_[r]  += __shfl_xor(sq_[r], m);
            }
        float mean[4], rstd[4];
#pragma unroll
        for (int r = 0; r < 4; r++) {
            mean[r] = sum_[r] * (1.f / 128.f);
            float var = sq_[r] * (1.f / 128.f) - mean[r] * mean[r];
            rstd[r] = rsqrtf(fmaxf(var, 0.f) + 1e-5f);
        }
        __bf16* hsp = hs + ((hh * 128 + b) * 128 + r0 + q4) * 128;
#pragma unroll
        for (int t = 0; t < 8; t++)
#pragma unroll
            for (int r = 0; r < 4; r++) {
                float y = (acc[t][r] - mean[r]) * rstd[r] * lgv[t] + lbv[t];
                hsp[r * 128 + t * 16 + l15] = (__bf16)(y * mw);
            }
    }
}

// ---------------------------------------------------------------------------
// 4) merge heads + prep next layer. Last layer writes f32 out = h[:,127,:].
// ---------------------------------------------------------------------------
__global__ void __launch_bounds__(128)
merge_kernel(const __bf16* __restrict__ hs, const float* __restrict__ mbp, int l,
             float* __restrict__ hf, __bf16* __restrict__ hb, float* __restrict__ invn,
             float* __restrict__ out, int last)
{
    __shared__ float sred[2];
    const int b = blockIdx.x & 127, s = blockIdx.x >> 7, d = threadIdx.x;

    float acc = mbp[l];
#pragma unroll
    for (int h = 0; h < 8; h++)
        acc += (float)hs[((h * 128 + b) * 128 + s) * 128 + d];

    float ss = block_sum_128(acc * acc, sred);

    const int o = (b * 128 + s) * 128 + d;
    hf[o] = acc;
    hb[o] = (__bf16)acc;
    if (d == 0) invn[b * 128 + s] = rsqrtf(ss);
    if (last && s == 127) out[b * 128 + d] = acc;
}

// ---------------------------------------------------------------------------
extern "C" void kernel_launch(void* const* d_in, const int* in_sizes, int n_in,
                              void* d_out, int out_size, void* d_ws, size_t ws_size,
                              hipStream_t stream)
{
    (void)in_sizes; (void)n_in; (void)out_size; (void)ws_size;

    const float* x   = (const float*)d_in[0];
    const float* ew  = (const float*)d_in[1];
    const float* eb  = (const float*)d_in[2];
    const float* ct  = (const float*)d_in[3];
    const float* g0  = (const float*)d_in[4];
    const float* b0  = (const float*)d_in[5];
    const float* vw  = (const float*)d_in[6];
    const float* vb  = (const float*)d_in[7];
    const float* lng = (const float*)d_in[8];
    const float* lnb = (const float*)d_in[9];
    const float* phi = (const float*)d_in[10];
    const float* mw  = (const float*)d_in[11];
    const float* mb  = (const float*)d_in[12];
    float* out = (float*)d_out;

    char* ws = (char*)d_ws;
    __bf16* wt   = (__bf16*)(ws);                 // 1,572,864
    float*  hf   = (float*)(ws + 1572864);        // 8,388,608
    __bf16* hb   = (__bf16*)(ws + 9961472);       // 4,194,304
    float*  invn = (float*)(ws + 14155776);       // 65,536
    __bf16* hs   = (__bf16*)(ws + 14221312);      // 33,554,432
    __bf16* cvwf = (__bf16*)(ws + 47775744);      // 1,572,864 (frag-major Vw)
    float2* csn  = (float2*)(ws + 49348608);      // 6,242,304  (~55.6 MB total)

    vw_frag_kernel<<<384, 256, 0, stream>>>(vw, cvwf);
    sincos_kernel<<<48 * 254, 64, 0, stream>>>(phi, csn);
    build_w_kernel<<<768, 64, 0, stream>>>(csn, wt);
    embed_kernel<<<16384, 128, 0, stream>>>(x, ew, eb, ct, g0, b0, hf, hb, invn);
    for (int l = 0; l < 6; l++) {
        attn_kernel<<<1024, 512, 0, stream>>>(l, hf, hb, invn, wt, cvwf, vb,
                                              lng, lnb, mw, hs);
        merge_kernel<<<16384, 128, 0, stream>>>(hs, mb, l, hf, hb, invn, out,
                                                (l == 5) ? 1 : 0);
    }
}

// Round 8
// 427.109 us; speedup vs baseline: 1.2489x; 1.0290x over previous
//
#include <hip/hip_runtime.h>
#include <hip/hip_bf16.h>

// ---------------------------------------------------------------------------
// Quantum ViT: B=128, T=127, D_IN=48, DK=S=128, H=8, L=6, P=8128
// Inputs: all float32. Output: float32 [B, DK]. bf16 MFMA internals.
//
// R8: build_w latency fix. R7 counters: 117K cyc / 126 iters = 930 cyc/iter =
// one HBM-miss latency per iteration (prefetch distance was ~112 cyc). Now:
// 16-layer groups, 3-slot register buffer, prefetch issued 2 groups (~900
// issue-cyc) ahead; 4 cols/block (1536 blocks = 1.5 waves/SIMD, 2x TLP).
// ---------------------------------------------------------------------------

typedef __bf16 bf16x8 __attribute__((ext_vector_type(8)));
typedef float  f32x4  __attribute__((ext_vector_type(4)));
typedef unsigned int u32;

// swizzled LDS index for a 128x128 bf16 tile: chunk(col/8) ^= row&15.
__device__ __forceinline__ int sidx(int row, int col)
{
    return row * 128 + ((((col >> 3) ^ (row & 15)) << 3) | (col & 7));
}

// ---------------------------------------------------------------------------
// 0) Vw f32 -> bf16, FRAGMENT-MAJOR: cvwf[((lh*8+t)*4+k0)*64+lane][8] holds
//    Vw[lh][t*16+(lane&15)][k0*32+(lane>>4)*8 .. +8].
// ---------------------------------------------------------------------------
__global__ void __launch_bounds__(256)
vw_frag_kernel(const float* __restrict__ vw, __bf16* __restrict__ cvwf)
{
    const int f    = blockIdx.x * 256 + threadIdx.x;   // 98304 frags
    const int lane = f & 63;
    const int k0   = (f >> 6) & 3;
    const int t    = (f >> 8) & 7;
    const int lh   = f >> 11;
    const int row  = t * 16 + (lane & 15);
    const int col  = k0 * 32 + (lane >> 4) * 8;

    const float* src = vw + (lh * 128 + row) * 128 + col;
    __bf16* dst = cvwf + f * 8;
#pragma unroll
    for (int j = 0; j < 8; j++) dst[j] = (__bf16)src[j];
}

// ---------------------------------------------------------------------------
// 0b) sincos table, layer-major, 256 layers (253 real + 3 identity pad):
//     csn[(mat*256 + t)*64 + j] = (cos,sin) for pair i=2j+(t&1) at layer t.
// ---------------------------------------------------------------------------
__global__ void __launch_bounds__(64)
sincos_kernel(const float* __restrict__ phi, float2* __restrict__ csn)
{
    const int mat = blockIdx.x >> 8;
    const int t   = blockIdx.x & 255;
    const int j   = threadIdx.x;

    float th = 0.f;
    if (t < 253) {
        const int p = t & 1, i = 2 * j + p;
        const int lim = min(t, 252 - t);
        if (i <= lim) {
            const int k = (t + i) >> 1;
            th = phi[mat * 8128 + ((k * (k + 1)) >> 1) + (k - i)];
        }
    }
    float sn, cs;
    __sincosf(th, &sn, &cs);
    csn[(mat * 256 + t) * 64 + j] = make_float2(cs, sn);
}

// ---------------------------------------------------------------------------
// 1) W build: 253 parallel Givens layers (time(k,i)=2k-i; program order
//    preserved for every wire-sharing pair). Lane lam holds components
//    (2lam, 2lam+1) of 4 columns. Even layer: in-lane; odd: shfl exchange.
//    16-layer groups, 3-slot register buffer, prefetch 2 groups ahead.
//    Output Wt[mat][c][d] = W[d][c] (bf16, B-operand layout).
// ---------------------------------------------------------------------------
__global__ void __launch_bounds__(64)
build_w_kernel(const float2* __restrict__ csn, __bf16* __restrict__ wt)
{
    const int mat = blockIdx.x >> 5;   // 48 matrices
    const int grp = blockIdx.x & 31;   // 32 groups of 4 columns
    const int c0  = grp * 4;
    const int lam = threadIdx.x;

    const float2* base = csn + (mat * 256) * 64 + lam;

    float vlo[4], vhi[4];
#pragma unroll
    for (int j = 0; j < 4; j++) {
        vlo[j] = (2 * lam     == c0 + j) ? 1.f : 0.f;
        vhi[j] = (2 * lam + 1 == c0 + j) ? 1.f : 0.f;
    }

    float2 buf[3][16];
#pragma unroll
    for (int k = 0; k < 16; k++) buf[0][k] = base[k * 64];
#pragma unroll
    for (int k = 0; k < 16; k++) buf[1][k] = base[(16 + k) * 64];

#pragma unroll
    for (int g = 0; g < 16; g++) {
        const int cb = g % 3;
        if (g < 14) {
            const int nb = (g + 2) % 3;
#pragma unroll
            for (int k = 0; k < 16; k++)
                buf[nb][k] = base[((g + 2) * 16 + k) * 64];
        }
#pragma unroll
        for (int p = 0; p < 8; p++) {
            {   // even layer 16g+2p: pairs (2lam, 2lam+1) in-lane
                const float cs = buf[cb][2 * p].x, sn = buf[cb][2 * p].y;
#pragma unroll
                for (int j = 0; j < 4; j++) {
                    float lo = vlo[j], hi = vhi[j];
                    vlo[j] = cs * lo - sn * hi;
                    vhi[j] = sn * lo + cs * hi;
                }
            }
            {   // odd layer 16g+2p+1: pairs (2lam+1, 2lam+2) cross-lane
                const float cs = buf[cb][2 * p + 1].x, sn = buf[cb][2 * p + 1].y;
#pragma unroll
                for (int j = 0; j < 4; j++) {
                    float y  = __shfl_down(vlo[j], 1);   // W[2lam+2][c]
                    float x  = vhi[j];                   // W[2lam+1][c]
                    float xn = cs * x - sn * y;
                    float yn = sn * x + cs * y;
                    vhi[j] = xn;
                    float z = __shfl_up(yn, 1);          // new W[2lam][c]
                    if (lam > 0) vlo[j] = z;
                }
            }
        }
    }

    u32* wtu = (u32*)wt;
#pragma unroll
    for (int j = 0; j < 4; j++) {
        __bf16 va = (__bf16)vlo[j];
        __bf16 vb = (__bf16)vhi[j];
        u32 pk = (u32)__builtin_bit_cast(unsigned short, va)
               | ((u32)__builtin_bit_cast(unsigned short, vb) << 16);
        wtu[mat * 8192 + (c0 + j) * 64 + lam] = pk;
    }
}

// ---------------------------------------------------------------------------
static __device__ __forceinline__ float block_sum_128(float v, float* sred)
{
#pragma unroll
    for (int m = 32; m; m >>= 1) v += __shfl_xor(v, m);
    __syncthreads();
    if ((threadIdx.x & 63) == 0) sred[threadIdx.x >> 6] = v;
    __syncthreads();
    return sred[0] + sred[1];
}

// ---------------------------------------------------------------------------
// 2) embed: tok = x @ Ew^T + eb (class token s=0), LN0 -> h_f32/h_bf16/inv_n
// ---------------------------------------------------------------------------
__global__ void __launch_bounds__(128)
embed_kernel(const float* __restrict__ x,  const float* __restrict__ ew,
             const float* __restrict__ eb, const float* __restrict__ ct,
             const float* __restrict__ g0, const float* __restrict__ b0,
             float* __restrict__ hf, __bf16* __restrict__ hb, float* __restrict__ invn)
{
    __shared__ float sx[48];
    __shared__ float sred[2];
    const int b = blockIdx.x & 127, s = blockIdx.x >> 7, d = threadIdx.x;

    float val;
    if (s == 0) {
        val = ct[d];
    } else {
        if (d < 48) sx[d] = x[(b * 127 + (s - 1)) * 48 + d];
        __syncthreads();
        float aa = 0.f;
#pragma unroll
        for (int f = 0; f < 48; f++) aa = fmaf(sx[f], ew[d * 48 + f], aa);
        val = aa + eb[d];
    }
    float mean = block_sum_128(val, sred) * (1.f / 128.f);
    float xc   = val - mean;
    float var  = block_sum_128(xc * xc, sred) * (1.f / 128.f);
    float y    = xc * rsqrtf(var + 1e-5f) * g0[d] + b0[d];
    float ss   = block_sum_128(y * y, sred);

    const int o = (b * 128 + s) * 128 + d;
    hf[o] = y;
    hb[o] = (__bf16)y;
    if (d == 0) invn[b * 128 + s] = rsqrtf(ss);
}

// ---------------------------------------------------------------------------
// 3) fused attention head: one WG per (head, batch). 512 thr = 8 waves,
//    wave w owns rows w*16..w*16+15 of every 128x128 matmul.
//    LDS: sH (h -> V^T) + sY (Wt -> T1 -> Pm). Vw B-frags from global.
//    A: T1 = h @ W        | B: G = T1 @ h^T, softmax -> Pm
//    C: V = h @ Vw^T      | D: O = Pm @ V, +h, LN, *mw -> hs
//    scores = G^2 * inv_ns * inv_nt * scale  (softmax in base 2)
// ---------------------------------------------------------------------------
__global__ void __launch_bounds__(512, 4)
attn_kernel(int l,
            const float*  __restrict__ hf,  const __bf16* __restrict__ hb,
            const float*  __restrict__ invn, const __bf16* __restrict__ wt,
            const __bf16* __restrict__ vwf, const float* __restrict__ vb,
            const float* __restrict__ lng,  const float* __restrict__ lnb,
            const float* __restrict__ mwp,  __bf16* __restrict__ hs)
{
    __shared__ __align__(16) __bf16 sH[128 * 128];
    __shared__ __align__(16) __bf16 sY[128 * 128];
    __shared__ float sInv[128];
    __shared__ float sVb[128];
    __shared__ float sLg[128];
    __shared__ float sLb[128];

    const int tid  = threadIdx.x;
    const int lane = tid & 63, w = tid >> 6;
    const int l15  = lane & 15, quad = lane >> 4;
    const int b    = blockIdx.x & 127;   // XCD = b%8 -> ~2 MB/XCD working set
    const int hh   = blockIdx.x >> 7;
    const int lh   = l * 8 + hh;

    const __bf16* hbp = hb + b * 16384;
    const __bf16* wtp = wt + lh * 16384;

    // ---- stage sH (h) + sY (Wt), swizzled ----
#pragma unroll
    for (int c = 0; c < 4; c++) {
        int ch  = tid + c * 512;          // 2048 chunks of 8 bf16
        int row = ch >> 4, cc = ch & 15;
        bf16x8 hv = *(const bf16x8*)(hbp + ch * 8);
        bf16x8 wv = *(const bf16x8*)(wtp + ch * 8);
        *(bf16x8*)(&sH[sidx(row, cc * 8)]) = hv;
        *(bf16x8*)(&sY[sidx(row, cc * 8)]) = wv;
    }
    if (tid < 128) {
        sInv[tid] = invn[b * 128 + tid];
        sVb[tid]  = vb[lh * 128 + tid];
        sLg[tid]  = lng[lh * 128 + tid];
        sLb[tid]  = lnb[lh * 128 + tid];
    }
    __syncthreads();  // B1

    const int r0 = w * 16;               // this wave's 16 output rows
    const int kq = quad * 8;             // frag k-offset
    const int q4 = quad * 4;             // C/D row offset within 16-tile
    const f32x4 vzero = {0.f, 0.f, 0.f, 0.f};

    f32x4 acc[8];

    // 16x128 strip of a 128x128 matmul
    auto mmL = [&](const __bf16* Ab, const __bf16* Bb) {
#pragma unroll
        for (int t = 0; t < 8; t++) acc[t] = vzero;
#pragma unroll
        for (int k0 = 0; k0 < 128; k0 += 32) {
            const int kk = k0 + kq;
            bf16x8 a0 = *(const bf16x8*)(&Ab[sidx(r0 + l15, kk)]);
#pragma unroll
            for (int t = 0; t < 8; t++) {
                bf16x8 bb = *(const bf16x8*)(&Bb[sidx(t * 16 + l15, kk)]);
                acc[t] = __builtin_amdgcn_mfma_f32_16x16x32_bf16(a0, bb, acc[t], 0, 0, 0);
            }
        }
    };

    // ================= Phase A: T1 = h @ W =================
    mmL(sH, sY);
    __syncthreads();  // B2: all waves done reading sY(Wt)
#pragma unroll
    for (int t = 0; t < 8; t++)
#pragma unroll
        for (int r = 0; r < 4; r++)
            sY[sidx(r0 + q4 + r, t * 16 + l15)] = (__bf16)acc[t][r];
    // no barrier: phase B reads only this wave's own T1 rows

    // ================= Phase B: G = T1 @ h^T =================
    mmL(sY, sH);

    // ---- softmax (base 2): v = G^2*inv_s*inv_t*(scale*log2e) -> Pm in sY ---
    {
        const float scale2 = 0.08838834764831843f * 1.4426950408889634f;
        float invt[8];
#pragma unroll
        for (int t = 0; t < 8; t++) invt[t] = sInv[t * 16 + l15];
        float invs[4];
#pragma unroll
        for (int r = 0; r < 4; r++) invs[r] = sInv[r0 + q4 + r];

        float mx[4] = {-3e38f, -3e38f, -3e38f, -3e38f};
#pragma unroll
        for (int t = 0; t < 8; t++)
#pragma unroll
            for (int r = 0; r < 4; r++) {
                float g = acc[t][r];
                float v = g * g * invs[r] * invt[t] * scale2;
                acc[t][r] = v;
                mx[r] = fmaxf(mx[r], v);
            }
#pragma unroll
        for (int m = 1; m < 16; m <<= 1)
#pragma unroll
            for (int r = 0; r < 4; r++) mx[r] = fmaxf(mx[r], __shfl_xor(mx[r], m));

        float sm[4] = {0.f, 0.f, 0.f, 0.f};
#pragma unroll
        for (int t = 0; t < 8; t++)
#pragma unroll
            for (int r = 0; r < 4; r++) {
                float e = exp2f(acc[t][r] - mx[r]);
                acc[t][r] = e;
                sm[r] += e;
            }
#pragma unroll
        for (int m = 1; m < 16; m <<= 1)
#pragma unroll
            for (int r = 0; r < 4; r++) sm[r] += __shfl_xor(sm[r], m);
#pragma unroll
        for (int r = 0; r < 4; r++) sm[r] = 1.0f / sm[r];
#pragma unroll
        for (int t = 0; t < 8; t++)
#pragma unroll
            for (int r = 0; r < 4; r++)
                sY[sidx(r0 + q4 + r, t * 16 + l15)] = (__bf16)(acc[t][r] * sm[r]);
    }

    // residual prefetch (consumed in epilogue)
    float hres[8][4];
    {
        const float* hfp = hf + (b * 128 + r0 + q4) * 128;
#pragma unroll
        for (int t = 0; t < 8; t++)
#pragma unroll
            for (int r = 0; r < 4; r++)
                hres[t][r] = hfp[r * 128 + t * 16 + l15];
    }

    // ================= Phase C: V = h @ Vw^T (B-frags from global) ========
    {
        const __bf16* vbase = vwf + (size_t)lh * 16384;  // frag-major head blk
#pragma unroll
        for (int t = 0; t < 8; t++) acc[t] = vzero;
#pragma unroll
        for (int k0c = 0; k0c < 4; k0c++) {
            const int kk = k0c * 32 + kq;
            bf16x8 a0 = *(const bf16x8*)(&sH[sidx(r0 + l15, kk)]);
#pragma unroll
            for (int t = 0; t < 8; t++) {
                bf16x8 bb = *(const bf16x8*)(vbase + ((t * 4 + k0c) * 64 + lane) * 8);
                acc[t] = __builtin_amdgcn_mfma_f32_16x16x32_bf16(a0, bb, acc[t], 0, 0, 0);
            }
        }
    }
    __syncthreads();  // B4: all waves done reading sH (phases B & C)

    {   // V^T into sH: sH[e][token]
        float vbv[8];
#pragma unroll
        for (int t = 0; t < 8; t++) vbv[t] = sVb[t * 16 + l15];
#pragma unroll
        for (int t = 0; t < 8; t++)
#pragma unroll
            for (int r = 0; r < 4; r++)
                sH[sidx(t * 16 + l15, r0 + q4 + r)] = (__bf16)(acc[t][r] + vbv[t]);
    }
    __syncthreads();  // B5

    // ================= Phase D: O = Pm @ V =================
    mmL(sY, sH);

    {   // epilogue: +h, LN over d, *merger_w -> hs
        const float mw = mwp[lh];
        float lgv[8], lbv[8];
#pragma unroll
        for (int t = 0; t < 8; t++) {
            lgv[t] = sLg[t * 16 + l15];
            lbv[t] = sLb[t * 16 + l15];
        }
        float sum_[4] = {0.f, 0.f, 0.f, 0.f};
        float sq_[4]  = {0.f, 0.f, 0.f, 0.f};
#pragma unroll
        for (int t = 0; t < 8; t++)
#pragma unroll
            for (int r = 0; r < 4; r++) {
                float xx = acc[t][r] + hres[t][r];
                acc[t][r] = xx;
                sum_[r] += xx;
                sq_[r]  += xx * xx;
            }
#pragma unroll
        for (int m = 1; m < 16; m <<= 1)
#pragma unroll
            for (int r = 0; r < 4; r++) {
                sum_[r] += __shfl_xor(sum_[r], m);
                sq_[r]  += __shfl_xor(sq_[r], m);
            }
        float mean[4], rstd[4];
#pragma unroll
        for (int r = 0; r < 4; r++) {
            mean[r] = sum_[r] * (1.f / 128.f);
            float var = sq_[r] * (1.f / 128.f) - mean[r] * mean[r];
            rstd[r] = rsqrtf(fmaxf(var, 0.f) + 1e-5f);
        }
        __bf16* hsp = hs + ((hh * 128 + b) * 128 + r0 + q4) * 128;
#pragma unroll
        for (int t = 0; t < 8; t++)
#pragma unroll
            for (int r = 0; r < 4; r++) {
                float y = (acc[t][r] - mean[r]) * rstd[r] * lgv[t] + lbv[t];
                hsp[r * 128 + t * 16 + l15] = (__bf16)(y * mw);
            }
    }
}

// ---------------------------------------------------------------------------
// 4) merge heads + prep next layer. Last layer writes f32 out = h[:,127,:].
// ---------------------------------------------------------------------------
__global__ void __launch_bounds__(128)
merge_kernel(const __bf16* __restrict__ hs, const float* __restrict__ mbp, int l,
             float* __restrict__ hf, __bf16* __restrict__ hb, float* __restrict__ invn,
             float* __restrict__ out, int last)
{
    __shared__ float sred[2];
    const int b = blockIdx.x & 127, s = blockIdx.x >> 7, d = threadIdx.x;

    float acc = mbp[l];
#pragma unroll
    for (int h = 0; h < 8; h++)
        acc += (float)hs[((h * 128 + b) * 128 + s) * 128 + d];

    float ss = block_sum_128(acc * acc, sred);

    const int o = (b * 128 + s) * 128 + d;
    hf[o] = acc;
    hb[o] = (__bf16)acc;
    if (d == 0) invn[b * 128 + s] = rsqrtf(ss);
    if (last && s == 127) out[b * 128 + d] = acc;
}

// ---------------------------------------------------------------------------
extern "C" void kernel_launch(void* const* d_in, const int* in_sizes, int n_in,
                              void* d_out, int out_size, void* d_ws, size_t ws_size,
                              hipStream_t stream)
{
    (void)in_sizes; (void)n_in; (void)out_size; (void)ws_size;

    const float* x   = (const float*)d_in[0];
    const float* ew  = (const float*)d_in[1];
    const float* eb  = (const float*)d_in[2];
    const float* ct  = (const float*)d_in[3];
    const float* g0  = (const float*)d_in[4];
    const float* b0  = (const float*)d_in[5];
    const float* vw  = (const float*)d_in[6];
    const float* vb  = (const float*)d_in[7];
    const float* lng = (const float*)d_in[8];
    const float* lnb = (const float*)d_in[9];
    const float* phi = (const float*)d_in[10];
    const float* mw  = (const float*)d_in[11];
    const float* mb  = (const float*)d_in[12];
    float* out = (float*)d_out;

    char* ws = (char*)d_ws;
    __bf16* wt   = (__bf16*)(ws);                 // 1,572,864
    float*  hf   = (float*)(ws + 1572864);        // 8,388,608
    __bf16* hb   = (__bf16*)(ws + 9961472);       // 4,194,304
    float*  invn = (float*)(ws + 14155776);       // 65,536
    __bf16* hs   = (__bf16*)(ws + 14221312);      // 33,554,432
    __bf16* cvwf = (__bf16*)(ws + 47775744);      // 1,572,864 (frag-major Vw)
    float2* csn  = (float2*)(ws + 49348608);      // 48*256*64*8 = 6,291,456
                                                  // total ~55.6 MB

    vw_frag_kernel<<<384, 256, 0, stream>>>(vw, cvwf);
    sincos_kernel<<<48 * 256, 64, 0, stream>>>(phi, csn);
    build_w_kernel<<<1536, 64, 0, stream>>>(csn, wt);
    embed_kernel<<<16384, 128, 0, stream>>>(x, ew, eb, ct, g0, b0, hf, hb, invn);
    for (int l = 0; l < 6; l++) {
        attn_kernel<<<1024, 512, 0, stream>>>(l, hf, hb, invn, wt, cvwf, vb,
                                              lng, lnb, mw, hs);
        merge_kernel<<<16384, 128, 0, stream>>>(hs, mb, l, hf, hb, invn, out,
                                                (l == 5) ? 1 : 0);
    }
}